// Round 1
// baseline (956.659 us; speedup 1.0000x reference)
//
#include <hip/hip_runtime.h>

// QuantMatMul: fake-quant(A) @ fake-quant(B), computed exactly via i8 MFMA.
// A: [4,4096,4096] fp32 -> folded to M=16384 rows. B: [4096,4096] fp32 (K x N).
// C = s_a*s_b * ( A'B' - zb*rowsumA[m] - za*colsumB[n] + K*za*zb ),  A',B' in i8.

#define K_DIM 4096
#define N_COLS 4096
#define M_ROWS 16384

typedef __attribute__((ext_vector_type(4))) int int4v;

struct QParams { float sa, zpa, sb, zpb, sab; int za, zb; };

// ---- workspace layout (total ~80.1 MiB) ----
static const size_t OFF_AQ = 0;                                  // 64 MiB  i8 [16384][4096]
static const size_t OFF_BT = (size_t)64 << 20;                   // 16 MiB  i8 [4096][4096] (B^T)
static const size_t OFF_RS = OFF_BT + ((size_t)16 << 20);        // 64 KiB  int rowsumA
static const size_t OFF_CS = OFF_RS + (size_t)M_ROWS * 4;        // 16 KiB  int colsumB
static const size_t OFF_MM = OFF_CS + (size_t)N_COLS * 4;        // 64 B    minmax enc
static const size_t OFF_PR = OFF_MM + 64;                        // params

// sortable encoding for float atomic min/max
__device__ __forceinline__ unsigned enc_f(float f) {
  unsigned u = __float_as_uint(f);
  return (u & 0x80000000u) ? ~u : (u | 0x80000000u);
}
__device__ __forceinline__ float dec_f(unsigned e) {
  unsigned u = (e & 0x80000000u) ? (e & 0x7fffffffu) : ~e;
  return __uint_as_float(u);
}

__device__ __forceinline__ int quantize1(float x, float s, float zp) {
  // matches ref: clip(rint(x/s) + zp, 0, 255), then shift by -128 into i8 range
  return (int)(fminf(fmaxf(rintf(x / s) + zp, 0.0f), 255.0f)) - 128;
}

__device__ __forceinline__ void gload16(const void* g, void* l) {
  __builtin_amdgcn_global_load_lds(
      (const __attribute__((address_space(1))) unsigned int*)g,
      (__attribute__((address_space(3))) unsigned int*)l, 16, 0, 0);
}

__global__ void init_mm_k(unsigned* mm) {
  if (threadIdx.x == 0) {
    mm[0] = 0xFFFFFFFFu; mm[1] = 0u;   // A min/max (encoded)
    mm[2] = 0xFFFFFFFFu; mm[3] = 0u;   // B min/max
  }
}

__global__ __launch_bounds__(256) void minmax_k(const float4* __restrict__ x, long n4,
                                                unsigned* __restrict__ mm) {
  float lo = 3.402823466e38f, hi = -3.402823466e38f;
  long i = (long)blockIdx.x * blockDim.x + threadIdx.x;
  const long stride = (long)gridDim.x * blockDim.x;
  for (; i < n4; i += stride) {
    float4 v = x[i];
    lo = fminf(lo, fminf(fminf(v.x, v.y), fminf(v.z, v.w)));
    hi = fmaxf(hi, fmaxf(fmaxf(v.x, v.y), fmaxf(v.z, v.w)));
  }
  for (int off = 32; off; off >>= 1) {
    lo = fminf(lo, __shfl_down(lo, off));
    hi = fmaxf(hi, __shfl_down(hi, off));
  }
  __shared__ float slo[4], shi[4];
  const int t = threadIdx.x;
  if ((t & 63) == 0) { slo[t >> 6] = lo; shi[t >> 6] = hi; }
  __syncthreads();
  if (t == 0) {
    for (int w = 1; w < 4; w++) { lo = fminf(lo, slo[w]); hi = fmaxf(hi, shi[w]); }
    atomicMin(&mm[0], enc_f(lo));
    atomicMax(&mm[1], enc_f(hi));
  }
}

__global__ void params_k(const unsigned* __restrict__ mm, QParams* __restrict__ p) {
  if (threadIdx.x != 0) return;
  const float amin = dec_f(mm[0]), amax = dec_f(mm[1]);
  const float bmin = dec_f(mm[2]), bmax = dec_f(mm[3]);
  const float sa = fmaxf((amax - amin) / 255.0f, 1e-8f);
  const float sb = fmaxf((bmax - bmin) / 255.0f, 1e-8f);
  const float zpa = rintf(-amin / sa);
  const float zpb = rintf(-bmin / sb);
  p->sa = sa; p->zpa = zpa; p->sb = sb; p->zpb = zpb;
  p->sab = sa * sb;
  p->za = (int)zpa - 128;
  p->zb = (int)zpb - 128;
}

// one block per row: quantize 4096 fp32 -> i8 (shifted) + row sum of A'
__global__ __launch_bounds__(256) void quantA_k(const float* __restrict__ A,
                                                signed char* __restrict__ Aq,
                                                int* __restrict__ rowsum,
                                                const QParams* __restrict__ p) {
  const float sa = p->sa, zpa = p->zpa;
  const int row = blockIdx.x, t = threadIdx.x;
  const float4* src = (const float4*)(A + (size_t)row * K_DIM);
  unsigned* dst = (unsigned*)(Aq + (size_t)row * K_DIM);
  int sum = 0;
#pragma unroll
  for (int j = 0; j < 4; j++) {
    float4 v = src[j * 256 + t];
    int q0 = quantize1(v.x, sa, zpa);
    int q1 = quantize1(v.y, sa, zpa);
    int q2 = quantize1(v.z, sa, zpa);
    int q3 = quantize1(v.w, sa, zpa);
    sum += q0 + q1 + q2 + q3;
    dst[j * 256 + t] = ((unsigned)q0 & 255u) | (((unsigned)q1 & 255u) << 8) |
                       (((unsigned)q2 & 255u) << 16) | (((unsigned)q3 & 255u) << 24);
  }
  for (int off = 32; off; off >>= 1) sum += __shfl_down(sum, off);
  __shared__ int sw[4];
  if ((t & 63) == 0) sw[t >> 6] = sum;
  __syncthreads();
  if (t == 0) rowsum[row] = sw[0] + sw[1] + sw[2] + sw[3];
}

// quantize B and transpose to Bt[N][K] via 64x64 LDS tile
__global__ __launch_bounds__(256) void quantB_k(const float* __restrict__ B,
                                                signed char* __restrict__ Bt,
                                                const QParams* __restrict__ p) {
  const float sb = p->sb, zpb = p->zpb;
  __shared__ unsigned char s[64][72];
  const int n0 = blockIdx.x * 64, k0 = blockIdx.y * 64;
  const int t = threadIdx.x;
  const int kr = t >> 2, tl = t & 3;
  const float* rowp = B + (size_t)(k0 + kr) * N_COLS + n0;
#pragma unroll
  for (int j = 0; j < 4; j++) {
    const int fi = tl + j * 4;
    float4 v = *(const float4*)(rowp + fi * 4);
    int q0 = quantize1(v.x, sb, zpb);
    int q1 = quantize1(v.y, sb, zpb);
    int q2 = quantize1(v.z, sb, zpb);
    int q3 = quantize1(v.w, sb, zpb);
    *(unsigned*)&s[kr][fi * 4] = ((unsigned)q0 & 255u) | (((unsigned)q1 & 255u) << 8) |
                                 (((unsigned)q2 & 255u) << 16) | (((unsigned)q3 & 255u) << 24);
  }
  __syncthreads();
  const int nr = t >> 2, kb = tl * 16;
  unsigned w[4];
#pragma unroll
  for (int jj = 0; jj < 4; jj++) {
    unsigned b0 = s[kb + jj * 4 + 0][nr];
    unsigned b1 = s[kb + jj * 4 + 1][nr];
    unsigned b2 = s[kb + jj * 4 + 2][nr];
    unsigned b3 = s[kb + jj * 4 + 3][nr];
    w[jj] = b0 | (b1 << 8) | (b2 << 16) | (b3 << 24);
  }
  int4v o = {(int)w[0], (int)w[1], (int)w[2], (int)w[3]};
  *(int4v*)(Bt + (size_t)(n0 + nr) * K_DIM + k0 + kb) = o;
}

// colsum of B' = rowsum of Bt (coalesced)
__global__ __launch_bounds__(256) void colsum_k(const signed char* __restrict__ Bt,
                                                int* __restrict__ colsum) {
  const int n = blockIdx.x, t = threadIdx.x;
  const int4v v = ((const int4v*)(Bt + (size_t)n * K_DIM))[t];
  int sum = 0;
#pragma unroll
  for (int c = 0; c < 4; c++) {
    unsigned w = (unsigned)v[c];
    sum += (int)(signed char)(w & 255u) + (int)(signed char)((w >> 8) & 255u) +
           (int)(signed char)((w >> 16) & 255u) + (int)(signed char)((w >> 24) & 255u);
  }
  for (int off = 32; off; off >>= 1) sum += __shfl_down(sum, off);
  __shared__ int sw[4];
  if ((t & 63) == 0) sw[t >> 6] = sum;
  __syncthreads();
  if (t == 0) colsum[n] = sw[0] + sw[1] + sw[2] + sw[3];
}

// i8 GEMM, m97 structure: 128x128 tile, BK=64, 4 waves 2x2, 16x16x64 i8 MFMA
__global__ __launch_bounds__(256) void gemm_k(const signed char* __restrict__ Aq,
                                              const signed char* __restrict__ Bt,
                                              float* __restrict__ C,
                                              const int* __restrict__ rowsum,
                                              const int* __restrict__ colsum,
                                              const QParams* __restrict__ p) {
  __shared__ signed char As[128 * 64];
  __shared__ signed char Bs[128 * 64];
  const int t = threadIdx.x;
  const int m0 = blockIdx.y * 128, n0 = blockIdx.x * 128;
  const int w = t >> 6, l = t & 63;
  const int wm = (w & 1) * 64, wn = (w >> 1) * 64;
  const int ml = l & 15, q = l >> 4;

  int4v acc[4][4] = {};

  const int off0 = t * 16;                     // staging byte offset, round 0
  const int srow = off0 >> 6, scol = off0 & 63;
  const signed char* gA = Aq + (size_t)(m0 + srow) * K_DIM + scol;
  const signed char* gB = Bt + (size_t)(n0 + srow) * K_DIM + scol;
  signed char* lA = As + off0;
  signed char* lB = Bs + off0;

  const signed char* pa = As + (wm + ml) * 64 + q * 16;
  const signed char* pb = Bs + (wn + ml) * 64 + q * 16;

  for (int kt = 0; kt < 64; kt++) {
    const size_t kof = (size_t)kt * 64;
    gload16(gA + kof, lA);
    gload16(gA + (size_t)64 * K_DIM + kof, lA + 4096);
    gload16(gB + kof, lB);
    gload16(gB + (size_t)64 * K_DIM + kof, lB + 4096);
    __syncthreads();

    int4v a[4], b[4];
#pragma unroll
    for (int i = 0; i < 4; i++) a[i] = *(const int4v*)(pa + i * 1024);
#pragma unroll
    for (int j = 0; j < 4; j++) b[j] = *(const int4v*)(pb + j * 1024);
#pragma unroll
    for (int i = 0; i < 4; i++)
#pragma unroll
      for (int j = 0; j < 4; j++)
        acc[i][j] = __builtin_amdgcn_mfma_i32_16x16x64_i8(a[i], b[j], acc[i][j], 0, 0, 0);
    __syncthreads();
  }

  // epilogue: integer zero-point corrections (exact), then scale
  const float sab = p->sab;
  const int za = p->za, zb = p->zb;
  const int kzz = K_DIM * za * zb;
  const int gm0 = m0 + wm + q * 4;
  const int gnb = n0 + wn + ml;
  int cs[4];
#pragma unroll
  for (int j = 0; j < 4; j++) cs[j] = za * colsum[gnb + j * 16];
#pragma unroll
  for (int i = 0; i < 4; i++) {
    int rs[4];
#pragma unroll
    for (int r = 0; r < 4; r++) rs[r] = zb * rowsum[gm0 + i * 16 + r];
#pragma unroll
    for (int j = 0; j < 4; j++) {
#pragma unroll
      for (int r = 0; r < 4; r++) {
        const int v = acc[i][j][r] - rs[r] - cs[j] + kzz;
        C[(size_t)(gm0 + i * 16 + r) * N_COLS + (gnb + j * 16)] = sab * (float)v;
      }
    }
  }
}

extern "C" void kernel_launch(void* const* d_in, const int* in_sizes, int n_in,
                              void* d_out, int out_size, void* d_ws, size_t ws_size,
                              hipStream_t stream) {
  const float* A = (const float*)d_in[0];
  const float* B = (const float*)d_in[1];
  float* C = (float*)d_out;
  char* ws = (char*)d_ws;
  signed char* Aq = (signed char*)(ws + OFF_AQ);
  signed char* Bt = (signed char*)(ws + OFF_BT);
  int* rowsum = (int*)(ws + OFF_RS);
  int* colsum = (int*)(ws + OFF_CS);
  unsigned* mm = (unsigned*)(ws + OFF_MM);
  QParams* prm = (QParams*)(ws + OFF_PR);

  init_mm_k<<<1, 64, 0, stream>>>(mm);
  minmax_k<<<4096, 256, 0, stream>>>((const float4*)A, (long)M_ROWS * K_DIM / 4, mm + 0);
  minmax_k<<<2048, 256, 0, stream>>>((const float4*)B, (long)K_DIM * N_COLS / 4, mm + 2);
  params_k<<<1, 64, 0, stream>>>(mm, prm);
  quantA_k<<<M_ROWS, 256, 0, stream>>>(A, Aq, rowsum, prm);
  quantB_k<<<dim3(64, 64), 256, 0, stream>>>(B, Bt, prm);
  colsum_k<<<N_COLS, 256, 0, stream>>>(Bt, colsum);
  gemm_k<<<dim3(32, 128), 256, 0, stream>>>(Aq, Bt, C, rowsum, colsum, prm);
}

// Round 2
// 869.167 us; speedup vs baseline: 1.1007x; 1.1007x over previous
//
#include <hip/hip_runtime.h>

// QuantMatMul: fake-quant(A) @ fake-quant(B), computed exactly via i8 MFMA.
// A: [4,4096,4096] fp32 -> folded to M=16384 rows. B: [4096,4096] fp32 (K x N).
// C = s_a*s_b * ( A'B' - zb*rowsumA[m] - za*colsumB[n] + K*za*zb ),  A',B' in i8.
//
// Round 2: 32x32x32 i8 MFMA, BK=128, XOR-swizzled 16B K-blocks in the packed
// global layout (conflict-free LDS fragment reads, staging stays lane-linear),
// launch_bounds(256,4); quantization via reciprocal multiply; fused minmax.

#define K_DIM 4096
#define N_COLS 4096
#define M_ROWS 16384

typedef __attribute__((ext_vector_type(4))) int int4v;
typedef __attribute__((ext_vector_type(16))) int int16v;

struct QParams { float sa, zpa, sb, zpb, sab, ra, rb; int za, zb; };

// ---- workspace layout (total ~80.1 MiB) ----
static const size_t OFF_AQ = 0;                                  // 64 MiB  i8 [16384][4096] (swizzled)
static const size_t OFF_BT = (size_t)64 << 20;                   // 16 MiB  i8 [4096][4096] (B^T, swizzled)
static const size_t OFF_RS = OFF_BT + ((size_t)16 << 20);        // 64 KiB  int rowsumA
static const size_t OFF_CS = OFF_RS + (size_t)M_ROWS * 4;        // 16 KiB  int colsumB
static const size_t OFF_MM = OFF_CS + (size_t)N_COLS * 4;        // 64 B    minmax enc
static const size_t OFF_PR = OFF_MM + 64;                        // params

// sortable encoding for float atomic min/max
__device__ __forceinline__ unsigned enc_f(float f) {
  unsigned u = __float_as_uint(f);
  return (u & 0x80000000u) ? ~u : (u | 0x80000000u);
}
__device__ __forceinline__ float dec_f(unsigned e) {
  unsigned u = (e & 0x80000000u) ? (e & 0x7fffffffu) : ~e;
  return __uint_as_float(u);
}

// reciprocal-multiply quantize: matches ref's clip(rint(x/s)+zp,0,255), -128 shift
__device__ __forceinline__ int quantize1(float x, float r, float zp) {
  return (int)(fminf(fmaxf(rintf(x * r) + zp, 0.0f), 255.0f)) - 128;
}

__device__ __forceinline__ void gload16(const void* g, void* l) {
  __builtin_amdgcn_global_load_lds(
      (const __attribute__((address_space(1))) unsigned int*)g,
      (__attribute__((address_space(3))) unsigned int*)l, 16, 0, 0);
}

__global__ void init_mm_k(unsigned* mm) {
  if (threadIdx.x == 0) {
    mm[0] = 0xFFFFFFFFu; mm[1] = 0u;   // A min/max (encoded)
    mm[2] = 0xFFFFFFFFu; mm[3] = 0u;   // B min/max
  }
}

// fused minmax over A (blocks 0..4095) and B (blocks 4096..5119)
__global__ __launch_bounds__(256) void minmax_k(const float4* __restrict__ A,
                                                const float4* __restrict__ B,
                                                unsigned* __restrict__ mm) {
  const bool isB = blockIdx.x >= 4096;
  const float4* __restrict__ x = isB ? B : A;
  const long n4 = isB ? (long)K_DIM * N_COLS / 4 : (long)M_ROWS * K_DIM / 4;
  const int nblk = isB ? 1024 : 4096;
  const int bid = isB ? (int)blockIdx.x - 4096 : (int)blockIdx.x;
  unsigned* m = mm + (isB ? 2 : 0);

  float lo = 3.402823466e38f, hi = -3.402823466e38f;
  long i = (long)bid * blockDim.x + threadIdx.x;
  const long stride = (long)nblk * blockDim.x;
  for (; i < n4; i += stride) {
    float4 v = x[i];
    lo = fminf(lo, fminf(fminf(v.x, v.y), fminf(v.z, v.w)));
    hi = fmaxf(hi, fmaxf(fmaxf(v.x, v.y), fmaxf(v.z, v.w)));
  }
  for (int off = 32; off; off >>= 1) {
    lo = fminf(lo, __shfl_down(lo, off));
    hi = fmaxf(hi, __shfl_down(hi, off));
  }
  __shared__ float slo[4], shi[4];
  const int t = threadIdx.x;
  if ((t & 63) == 0) { slo[t >> 6] = lo; shi[t >> 6] = hi; }
  __syncthreads();
  if (t == 0) {
    for (int w = 1; w < 4; w++) { lo = fminf(lo, slo[w]); hi = fmaxf(hi, shi[w]); }
    atomicMin(&m[0], enc_f(lo));
    atomicMax(&m[1], enc_f(hi));
  }
}

__global__ void params_k(const unsigned* __restrict__ mm, QParams* __restrict__ p) {
  if (threadIdx.x != 0) return;
  const float amin = dec_f(mm[0]), amax = dec_f(mm[1]);
  const float bmin = dec_f(mm[2]), bmax = dec_f(mm[3]);
  const float sa = fmaxf((amax - amin) / 255.0f, 1e-8f);
  const float sb = fmaxf((bmax - bmin) / 255.0f, 1e-8f);
  const float zpa = rintf(-amin / sa);
  const float zpb = rintf(-bmin / sb);
  p->sa = sa; p->zpa = zpa; p->sb = sb; p->zpb = zpb;
  p->sab = sa * sb;
  p->ra = 1.0f / sa;
  p->rb = 1.0f / sb;
  p->za = (int)zpa - 128;
  p->zb = (int)zpb - 128;
}

// one block per row: quantize + XOR-swizzle 16B blocks within 128B spans + rowsum
__global__ __launch_bounds__(256) void quantA_k(const float* __restrict__ A,
                                                signed char* __restrict__ Aq,
                                                int* __restrict__ rowsum,
                                                const QParams* __restrict__ p) {
  const float ra = p->ra, zpa = p->zpa;
  const int row = blockIdx.x, t = threadIdx.x;
  const float4* src = (const float4*)(A + (size_t)row * K_DIM);
  unsigned* dst = (unsigned*)(Aq + (size_t)row * K_DIM);
  int sum = 0;
#pragma unroll
  for (int j = 0; j < 4; j++) {
    const int d = j * 256 + t;           // logical dword index in row (0..1023)
    float4 v = src[d];
    int q0 = quantize1(v.x, ra, zpa);
    int q1 = quantize1(v.y, ra, zpa);
    int q2 = quantize1(v.z, ra, zpa);
    int q3 = quantize1(v.w, ra, zpa);
    sum += q0 + q1 + q2 + q3;
    // swizzle: 16B block bits (d>>2)&7 XOR (row&7)
    const int dsw = (d & ~0x1C) | ((((d >> 2) ^ row) & 7) << 2);
    dst[dsw] = ((unsigned)q0 & 255u) | (((unsigned)q1 & 255u) << 8) |
               (((unsigned)q2 & 255u) << 16) | (((unsigned)q3 & 255u) << 24);
  }
  for (int off = 32; off; off >>= 1) sum += __shfl_down(sum, off);
  __shared__ int sw[4];
  if ((t & 63) == 0) sw[t >> 6] = sum;
  __syncthreads();
  if (t == 0) rowsum[row] = sw[0] + sw[1] + sw[2] + sw[3];
}

// quantize B, transpose to Bt[N][K] via 64x64 LDS tile, XOR-swizzle 16B blocks
__global__ __launch_bounds__(256) void quantB_k(const float* __restrict__ B,
                                                signed char* __restrict__ Bt,
                                                const QParams* __restrict__ p) {
  const float rb = p->rb, zpb = p->zpb;
  __shared__ unsigned char s[64][72];
  const int n0 = blockIdx.x * 64, k0 = blockIdx.y * 64;
  const int t = threadIdx.x;
  const int kr = t >> 2, tl = t & 3;
  const float* rowp = B + (size_t)(k0 + kr) * N_COLS + n0;
#pragma unroll
  for (int j = 0; j < 4; j++) {
    const int fi = tl + j * 4;
    float4 v = *(const float4*)(rowp + fi * 4);
    int q0 = quantize1(v.x, rb, zpb);
    int q1 = quantize1(v.y, rb, zpb);
    int q2 = quantize1(v.z, rb, zpb);
    int q3 = quantize1(v.w, rb, zpb);
    *(unsigned*)&s[kr][fi * 4] = ((unsigned)q0 & 255u) | (((unsigned)q1 & 255u) << 8) |
                                 (((unsigned)q2 & 255u) << 16) | (((unsigned)q3 & 255u) << 24);
  }
  __syncthreads();
  const int nr = t >> 2;                 // output row within tile (n)
  const int kb = tl * 16;                // 16-byte K block within 64B chunk
  unsigned w[4];
#pragma unroll
  for (int jj = 0; jj < 4; jj++) {
    unsigned b0 = s[kb + jj * 4 + 0][nr];
    unsigned b1 = s[kb + jj * 4 + 1][nr];
    unsigned b2 = s[kb + jj * 4 + 2][nr];
    unsigned b3 = s[kb + jj * 4 + 3][nr];
    w[jj] = b0 | (b1 << 8) | (b2 << 16) | (b3 << 24);
  }
  int4v o = {(int)w[0], (int)w[1], (int)w[2], (int)w[3]};
  const int bo = k0 + kb;                // logical byte offset in row
  const int bsw = (bo & ~0x70) | ((((bo >> 4) ^ nr) & 7) << 4);  // swizzled
  *(int4v*)(Bt + (size_t)(n0 + nr) * K_DIM + bsw) = o;
}

// colsum of B' = rowsum of Bt (swizzle is within-row permutation -> sum invariant)
__global__ __launch_bounds__(256) void colsum_k(const signed char* __restrict__ Bt,
                                                int* __restrict__ colsum) {
  const int n = blockIdx.x, t = threadIdx.x;
  const int4v v = ((const int4v*)(Bt + (size_t)n * K_DIM))[t];
  int sum = 0;
#pragma unroll
  for (int c = 0; c < 4; c++) {
    unsigned w = (unsigned)v[c];
    sum += (int)(signed char)(w & 255u) + (int)(signed char)((w >> 8) & 255u) +
           (int)(signed char)((w >> 16) & 255u) + (int)(signed char)((w >> 24) & 255u);
  }
  for (int off = 32; off; off >>= 1) sum += __shfl_down(sum, off);
  __shared__ int sw[4];
  if ((t & 63) == 0) sw[t >> 6] = sum;
  __syncthreads();
  if (t == 0) colsum[n] = sw[0] + sw[1] + sw[2] + sw[3];
}

// i8 GEMM: 128x128 tile, BK=128, 4 waves 2x2 (64x64/wave), 32x32x32 i8 MFMA,
// 2x2 32x32 accumulators per wave. Swizzled LDS reads are bank-spread.
__global__ __launch_bounds__(256, 4) void gemm_k(const signed char* __restrict__ Aq,
                                                 const signed char* __restrict__ Bt,
                                                 float* __restrict__ C,
                                                 const int* __restrict__ rowsum,
                                                 const int* __restrict__ colsum,
                                                 const QParams* __restrict__ p) {
  __shared__ signed char As[128 * 128];
  __shared__ signed char Bs[128 * 128];
  const int t = threadIdx.x;
  const int m0 = blockIdx.y * 128, n0 = blockIdx.x * 128;
  const int w = t >> 6, l = t & 63;
  const int wm = (w & 1) * 64, wn = (w >> 1) * 64;
  const int r32 = l & 31, h = l >> 5;    // row within 32-tile, K-half selector

  int16v acc[2][2] = {};

  const int off = t * 16;                 // staging byte offset (0..4080)
  const int srow = off >> 7, scol = off & 127;
  const signed char* gA = Aq + (size_t)(m0 + srow) * K_DIM + scol;
  const signed char* gB = Bt + (size_t)(n0 + srow) * K_DIM + scol;

  const int swz = (r32 & 7);              // row-dependent block swizzle

  for (int kt = 0; kt < 32; kt++) {
    const size_t kof = (size_t)kt * 128;
#pragma unroll
    for (int r = 0; r < 4; r++) {
      gload16(gA + (size_t)(32 * r) * K_DIM + kof, As + off + r * 4096);
      gload16(gB + (size_t)(32 * r) * K_DIM + kof, Bs + off + r * 4096);
    }
    __syncthreads();
#pragma unroll
    for (int s = 0; s < 4; s++) {
      const int ca = ((2 * s + h) ^ swz) << 4;   // swizzled 16B block within row
      int4v a0 = *(const int4v*)(As + (wm + r32) * 128 + ca);
      int4v a1 = *(const int4v*)(As + (wm + 32 + r32) * 128 + ca);
      int4v b0 = *(const int4v*)(Bs + (wn + r32) * 128 + ca);
      int4v b1 = *(const int4v*)(Bs + (wn + 32 + r32) * 128 + ca);
      acc[0][0] = __builtin_amdgcn_mfma_i32_32x32x32_i8(a0, b0, acc[0][0], 0, 0, 0);
      acc[0][1] = __builtin_amdgcn_mfma_i32_32x32x32_i8(a0, b1, acc[0][1], 0, 0, 0);
      acc[1][0] = __builtin_amdgcn_mfma_i32_32x32x32_i8(a1, b0, acc[1][0], 0, 0, 0);
      acc[1][1] = __builtin_amdgcn_mfma_i32_32x32x32_i8(a1, b1, acc[1][1], 0, 0, 0);
    }
    __syncthreads();
  }

  // epilogue: integer zero-point corrections (exact), then scale.
  // C/D layout (32x32): col = lane&31, row = (reg&3) + 8*(reg>>2) + 4*(lane>>5)
  const float sab = p->sab;
  const int za = p->za, zb = p->zb;
  const int kzz = K_DIM * za * zb;
#pragma unroll
  for (int j = 0; j < 2; j++) {
    const int col = n0 + wn + j * 32 + r32;
    const int cs = za * colsum[col];
#pragma unroll
    for (int i = 0; i < 2; i++) {
      const int rbase = m0 + wm + i * 32 + 4 * h;
#pragma unroll
      for (int r = 0; r < 16; r++) {
        const int row = rbase + (r & 3) + 8 * (r >> 2);
        const int v = acc[i][j][r] - zb * rowsum[row] - cs + kzz;
        C[(size_t)row * N_COLS + col] = sab * (float)v;
      }
    }
  }
}

extern "C" void kernel_launch(void* const* d_in, const int* in_sizes, int n_in,
                              void* d_out, int out_size, void* d_ws, size_t ws_size,
                              hipStream_t stream) {
  const float* A = (const float*)d_in[0];
  const float* B = (const float*)d_in[1];
  float* C = (float*)d_out;
  char* ws = (char*)d_ws;
  signed char* Aq = (signed char*)(ws + OFF_AQ);
  signed char* Bt = (signed char*)(ws + OFF_BT);
  int* rowsum = (int*)(ws + OFF_RS);
  int* colsum = (int*)(ws + OFF_CS);
  unsigned* mm = (unsigned*)(ws + OFF_MM);
  QParams* prm = (QParams*)(ws + OFF_PR);

  init_mm_k<<<1, 64, 0, stream>>>(mm);
  minmax_k<<<5120, 256, 0, stream>>>((const float4*)A, (const float4*)B, mm);
  params_k<<<1, 64, 0, stream>>>(mm, prm);
  quantA_k<<<M_ROWS, 256, 0, stream>>>(A, Aq, rowsum, prm);
  quantB_k<<<dim3(64, 64), 256, 0, stream>>>(B, Bt, prm);
  colsum_k<<<N_COLS, 256, 0, stream>>>(Bt, colsum);
  gemm_k<<<dim3(32, 128), 256, 0, stream>>>(Aq, Bt, C, rowsum, colsum, prm);
}